// Round 2
// baseline (1285.414 us; speedup 1.0000x reference)
//
#include <hip/hip_runtime.h>
#include <hip/hip_bf16.h>

#define B 8
#define CIN 64
#define COUT 64
#define S 512
#define H 256
#define W 256

// ---------------------------------------------------------------------------
// Kernel 1: style linear  y[b][c] = lin_b[c] + (1/sqrt(S)) * sum_s w[b,s]*lin_w[c,s]
// One wave (64 lanes) per (b,c) output; lane strides over s (coalesced loads).
// ---------------------------------------------------------------------------
__global__ void k_style(const float* __restrict__ w,
                        const float* __restrict__ lin_w,
                        const float* __restrict__ lin_b,
                        float* __restrict__ y) {
    int bc = blockIdx.x;          // b*64 + c
    int b = bc >> 6, c = bc & 63;
    int lane = threadIdx.x;       // 64 threads
    float acc = 0.f;
#pragma unroll
    for (int i = 0; i < S / 64; ++i) {
        int s = i * 64 + lane;
        acc += w[b * S + s] * lin_w[c * S + s];
    }
#pragma unroll
    for (int off = 32; off >= 1; off >>= 1) acc += __shfl_xor(acc, off, 64);
    if (lane == 0)
        y[bc] = acc * 0.04419417382415922f /* 1/sqrt(512) */ + lin_b[c];
}

// ---------------------------------------------------------------------------
// Kernel 2: modulate + demodulate.
// One wave per (b,co). lane = ci. Each lane holds its 9 taps:
//   v = conv_w[co,ci,k] * (1/24) * y[b,ci]
// demod = rsqrt(sum_{ci,k} v^2 + 1e-8)  (64-lane butterfly reduce)
// Store wm in layout [b][ci][co][k] (fp32) so the conv kernel's co-loop is
// contiguous + wave-uniform (scalar loads).
// ---------------------------------------------------------------------------
__global__ void k_weights(const float* __restrict__ conv_w,
                          const float* __restrict__ y,
                          float* __restrict__ wm) {
    int bco = blockIdx.x;          // b*64 + co
    int b = bco >> 6, co = bco & 63;
    int ci = threadIdx.x;          // 64 threads
    const float conv_scale = 1.0f / 24.0f;
    float yv = y[b * CIN + ci] * conv_scale;
    float wv[9];
    float ss = 0.f;
#pragma unroll
    for (int k = 0; k < 9; ++k) {
        float v = conv_w[(co * CIN + ci) * 9 + k] * yv;
        wv[k] = v;
        ss += v * v;
    }
#pragma unroll
    for (int off = 32; off >= 1; off >>= 1) ss += __shfl_xor(ss, off, 64);
    float demod = rsqrtf(ss + 1e-8f);
#pragma unroll
    for (int k = 0; k < 9; ++k)
        wm[((b * CIN + ci) * COUT + co) * 9 + k] = wv[k] * demod;
}

// ---------------------------------------------------------------------------
// Kernel 3: grouped 3x3 conv (pad 1) + noise + bias + leaky_relu*sqrt(2).
// Block: 32x8 output pixels of one batch b. Each thread: 1 pixel, all 64 co
// accumulators in registers. Per ci: stage 10x34 x-tile in LDS (fp32),
// read 3x3 neighborhood into regs, then 64 co * 9 FMAs with wave-uniform
// (scalar-loaded) weights from wm.
// ---------------------------------------------------------------------------
__global__ __launch_bounds__(256) void k_conv(
    const float* __restrict__ x,
    const float* __restrict__ wm,
    const float* __restrict__ noise,
    const float* __restrict__ nw_p,
    const float* __restrict__ act_bias,
    float* __restrict__ out) {
    __shared__ float xt[10][34];

    const int tx = threadIdx.x;             // 0..31
    const int ty = threadIdx.y;             // 0..7
    const int tid = ty * 32 + tx;
    const int wx = blockIdx.x * 32 + tx;
    const int hy = blockIdx.y * 8 + ty;
    const int b = blockIdx.z;
    const int h0 = blockIdx.y * 8 - 1;
    const int w0 = blockIdx.x * 32 - 1;

    float acc[COUT];
#pragma unroll
    for (int co = 0; co < COUT; ++co) acc[co] = 0.f;

    for (int ci = 0; ci < CIN; ++ci) {
        __syncthreads();
        const float* xp = x + (b * CIN + ci) * (H * W);
        for (int i = tid; i < 10 * 34; i += 256) {
            int r = i / 34;
            int c = i - r * 34;
            int gh = h0 + r, gw = w0 + c;
            float v = 0.f;
            if ((unsigned)gh < (unsigned)H && (unsigned)gw < (unsigned)W)
                v = xp[gh * W + gw];
            xt[r][c] = v;
        }
        __syncthreads();

        float xv[9];
#pragma unroll
        for (int dr = 0; dr < 3; ++dr)
#pragma unroll
            for (int dc = 0; dc < 3; ++dc)
                xv[dr * 3 + dc] = xt[ty + dr][tx + dc];

        const float* wp = wm + (b * CIN + ci) * (COUT * 9);
#pragma unroll
        for (int co = 0; co < COUT; ++co) {
            const float* q = wp + co * 9;
            float a = acc[co];
            a += xv[0] * q[0];
            a += xv[1] * q[1];
            a += xv[2] * q[2];
            a += xv[3] * q[3];
            a += xv[4] * q[4];
            a += xv[5] * q[5];
            a += xv[6] * q[6];
            a += xv[7] * q[7];
            a += xv[8] * q[8];
            acc[co] = a;
        }
    }

    const float nw = nw_p[0];
    const float add = nw * noise[(b * H + hy) * W + wx];
#pragma unroll
    for (int co = 0; co < COUT; ++co) {
        float v = acc[co] + add + act_bias[co];
        v = (v > 0.f ? v : 0.2f * v) * 1.41421356237f;
        out[((b * COUT + co) * H + hy) * W + wx] = v;
    }
}

extern "C" void kernel_launch(void* const* d_in, const int* in_sizes, int n_in,
                              void* d_out, int out_size, void* d_ws, size_t ws_size,
                              hipStream_t stream) {
    const float* x        = (const float*)d_in[0];
    const float* w        = (const float*)d_in[1];
    const float* noise    = (const float*)d_in[2];
    const float* lin_w    = (const float*)d_in[3];
    const float* lin_b    = (const float*)d_in[4];
    const float* conv_w   = (const float*)d_in[5];
    const float* nw_p     = (const float*)d_in[6];
    const float* act_bias = (const float*)d_in[7];

    float* y  = (float*)d_ws;              // 512 floats
    float* wm = y + 512;                   // 8*64*64*9 = 294912 floats

    k_style<<<B * CIN, 64, 0, stream>>>(w, lin_w, lin_b, y);
    k_weights<<<B * COUT, 64, 0, stream>>>(conv_w, y, wm);

    dim3 grid(W / 32, H / 8, B);           // (8, 32, 8) = 2048 blocks
    dim3 blk(32, 8);
    k_conv<<<grid, blk, 0, stream>>>(x, wm, noise, nw_p, act_bias,
                                     (float*)d_out);
}

// Round 3
// 425.177 us; speedup vs baseline: 3.0232x; 3.0232x over previous
//
#include <hip/hip_runtime.h>
#include <hip/hip_bf16.h>

#define Bn 8
#define Cc 64     // Cin = Cout
#define Hh 256
#define Ww 256
#define Ss 512

typedef __attribute__((ext_vector_type(8))) short short8;   // 8 bf16 (4 VGPRs)
typedef __attribute__((ext_vector_type(4))) float floatx4;  // MFMA C/D

// fp32 -> bf16 bits, round-to-nearest-even
__device__ __forceinline__ unsigned f2bf_bits(float f) {
    unsigned u = __float_as_uint(f);
    return (u + 0x7FFFu + ((u >> 16) & 1u)) >> 16;
}

// ---------------------------------------------------------------------------
// Kernel 1: style linear  y[b][c] = lin_b[c] + (1/sqrt(S)) * sum_s w[b,s]*lin_w[c,s]
// ---------------------------------------------------------------------------
__global__ void k_style(const float* __restrict__ w,
                        const float* __restrict__ lin_w,
                        const float* __restrict__ lin_b,
                        float* __restrict__ y) {
    int bc = blockIdx.x;          // b*64 + c
    int b = bc >> 6, c = bc & 63;
    int lane = threadIdx.x;       // 64 threads
    float acc = 0.f;
#pragma unroll
    for (int i = 0; i < Ss / 64; ++i) {
        int s = i * 64 + lane;
        acc += w[b * Ss + s] * lin_w[c * Ss + s];
    }
#pragma unroll
    for (int off = 32; off >= 1; off >>= 1) acc += __shfl_xor(acc, off, 64);
    if (lane == 0)
        y[bc] = acc * 0.04419417382415922f /* 1/sqrt(512) */ + lin_b[c];
}

// ---------------------------------------------------------------------------
// Kernel 2: modulate + demodulate; emit bf16 weights in MFMA A-fragment
// friendly layout:  wt[b][slab(2)][tap(9)][co(64)][ci_lo(32)]
// (slab = ci>>5).  A-frag load is then a single 16B global load per m-tile.
// ---------------------------------------------------------------------------
__global__ void k_weights(const float* __restrict__ conv_w,
                          const float* __restrict__ y,
                          short* __restrict__ wt) {
    int bco = blockIdx.x;          // b*64 + co
    int b = bco >> 6, co = bco & 63;
    int ci = threadIdx.x;          // 64 threads = ci
    const float conv_scale = 1.0f / 24.0f;   // 1/sqrt(64*9)
    float yv = y[b * Cc + ci] * conv_scale;
    float wv[9];
    float ss = 0.f;
#pragma unroll
    for (int k = 0; k < 9; ++k) {
        float v = conv_w[(co * Cc + ci) * 9 + k] * yv;
        wv[k] = v;
        ss += v * v;
    }
#pragma unroll
    for (int off = 32; off >= 1; off >>= 1) ss += __shfl_xor(ss, off, 64);
    float demod = rsqrtf(ss + 1e-8f);
    int s = ci >> 5, cl = ci & 31;
#pragma unroll
    for (int t = 0; t < 9; ++t)
        wt[(((b * 2 + s) * 9 + t) * Cc + co) * 32 + cl] =
            (short)f2bf_bits(wv[t] * demod);
}

// ---------------------------------------------------------------------------
// Kernel 3: implicit-GEMM conv via 9 tap-shifted GEMMs on bf16 MFMA.
//   out[co, p] = sum_t sum_ci W_t[co,ci] * x[ci, p + delta(t)]
// Block: one b, 64 co x (4h x 64w) pixel tile. Wave w -> row h0+w, 4 n-tiles
// of 16 px. K-loop: 2 ci-slabs x 9 taps, K=32 per MFMA (no padding).
// x staged fp32->bf16 into LDS [6 rows][66 cols][32 ci pad 40] (ci innermost
// so B-frag = 1x ds_read_b128). A-frags direct from L1/L2 (73 KB per b).
// MFMA 16x16x32 layouts (HW-verified per guide):
//   A[m=lane&15][k=quad*8+j], B[k=quad*8+j][n=lane&15],
//   D row = quad*4+reg, col = lane&15.
// ---------------------------------------------------------------------------
__global__ __launch_bounds__(256, 3) void k_mfma(
    const float* __restrict__ x,
    const short* __restrict__ wt,
    const float* __restrict__ noise,
    const float* __restrict__ nw_p,
    const float* __restrict__ act_bias,
    float* __restrict__ out) {
    __shared__ short xs[6 * 66 * 40];

    const int tid = threadIdx.x;
    const int wave = tid >> 6, lane = tid & 63;
    const int l15 = lane & 15, quad = lane >> 4;
    const int w0 = blockIdx.x * 64, h0 = blockIdx.y * 4, b = blockIdx.z;

    floatx4 acc[4][4];   // [m-tile][n-tile]
#pragma unroll
    for (int mt = 0; mt < 4; ++mt)
#pragma unroll
        for (int nt = 0; nt < 4; ++nt)
            acc[mt][nt] = (floatx4){0.f, 0.f, 0.f, 0.f};

    for (int s = 0; s < 2; ++s) {
        __syncthreads();   // xs reuse: previous slab's readers done
        // ---- stage 32 ci planes of the 6x66 halo tile, fp32->bf16, packed
        // cells: 16 ci-pairs x 6 rows x 66 cols = 6336 u32 cells
#pragma unroll
        for (int it = 0; it < 25; ++it) {
            int e = it * 256 + tid;
            if (e < 6336) {
                int c = e % 66;
                int rc = e / 66;
                int r = rc % 6;
                int cp = rc / 6;                 // ci pair 0..15
                int gh = h0 + r - 1, gw = w0 + c - 1;
                unsigned v = 0;
                if ((unsigned)gh < (unsigned)Hh && (unsigned)gw < (unsigned)Ww) {
                    const float* xp = x + (((size_t)(b * Cc + s * 32 + cp * 2) * Hh + gh) * Ww + gw);
                    unsigned lo = f2bf_bits(xp[0]);
                    unsigned hi = f2bf_bits(xp[Hh * Ww]);
                    v = lo | (hi << 16);
                }
                ((unsigned*)xs)[(r * 66 + c) * 20 + cp] = v;
            }
        }
        __syncthreads();

        const short* wbase = wt + (size_t)((b * 2 + s) * 9) * Cc * 32;
#pragma unroll
        for (int t = 0; t < 9; ++t) {
            const int dr = t / 3, dc = t % 3;
            short8 bfr[4];
#pragma unroll
            for (int nt = 0; nt < 4; ++nt)
                bfr[nt] = *(const short8*)(xs +
                    ((wave + dr) * 66 + (nt * 16 + l15 + dc)) * 40 + quad * 8);
            short8 afr[4];
#pragma unroll
            for (int mt = 0; mt < 4; ++mt)
                afr[mt] = *(const short8*)(wbase +
                    ((t * Cc + mt * 16 + l15) * 32 + quad * 8));
#pragma unroll
            for (int mt = 0; mt < 4; ++mt)
#pragma unroll
                for (int nt = 0; nt < 4; ++nt)
                    acc[mt][nt] = __builtin_amdgcn_mfma_f32_16x16x32_bf16(
                        afr[mt], bfr[nt], acc[mt][nt], 0, 0, 0);
        }
    }

    // ---- epilogue: noise + bias + leaky_relu * sqrt(2), fp32 store
    const int h = h0 + wave;
    const float nw = nw_p[0];
    float nz[4];
#pragma unroll
    for (int nt = 0; nt < 4; ++nt)
        nz[nt] = nw * noise[((size_t)b * Hh + h) * Ww + w0 + nt * 16 + l15];
#pragma unroll
    for (int mt = 0; mt < 4; ++mt) {
#pragma unroll
        for (int reg = 0; reg < 4; ++reg) {
            int co = mt * 16 + quad * 4 + reg;
            float bias = act_bias[co];
#pragma unroll
            for (int nt = 0; nt < 4; ++nt) {
                float v = acc[mt][nt][reg] + nz[nt] + bias;
                v = (v > 0.f ? v : 0.2f * v) * 1.41421356237f;
                out[(((size_t)(b * Cc + co)) * Hh + h) * Ww + w0 + nt * 16 + l15] = v;
            }
        }
    }
}

extern "C" void kernel_launch(void* const* d_in, const int* in_sizes, int n_in,
                              void* d_out, int out_size, void* d_ws, size_t ws_size,
                              hipStream_t stream) {
    const float* x        = (const float*)d_in[0];
    const float* w        = (const float*)d_in[1];
    const float* noise    = (const float*)d_in[2];
    const float* lin_w    = (const float*)d_in[3];
    const float* lin_b    = (const float*)d_in[4];
    const float* conv_w   = (const float*)d_in[5];
    const float* nw_p     = (const float*)d_in[6];
    const float* act_bias = (const float*)d_in[7];

    float* y  = (float*)d_ws;                       // 512 floats
    short* wtb = (short*)((char*)d_ws + 4096);      // 8*2*9*64*32 bf16 = 576 KB

    k_style<<<Bn * Cc, 64, 0, stream>>>(w, lin_w, lin_b, y);
    k_weights<<<Bn * Cc, 64, 0, stream>>>(conv_w, y, wtb);

    dim3 grid(Ww / 64, Hh / 4, Bn);                 // (4, 64, 8) = 2048 blocks
    k_mfma<<<grid, 256, 0, stream>>>(x, wtb, noise, nw_p, act_bias,
                                     (float*)d_out);
}